// Round 2
// baseline (697.465 us; speedup 1.0000x reference)
//
#include <hip/hip_runtime.h>
#include <hip/hip_bf16.h>
#include <stdint.h>

// SymbolicDecoder fused MLP evaluation, MI355X gfx950.  Round 2.
// Changes vs round 1:
//  - feat pre-converted to bf16 in d_ws (prep_feat); A staged via
//    global_load_lds (no in-loop f32->bf16 VALU work, half A bytes).
//  - block tile 128 rows x 256 cols, wave tile 64x128 (acc 4x8): per k-step
//    per wave 24 ds_read_b128 (~288cy) vs 64 MFMA (~310cy) -> MFMA-bound.
//  - bijective XCD swizzle (2816 blocks, %8==0) for A-tile L2 locality.
// d_ws layout (ushorts): [0, 6291456) prepped weights bf16 fragment-ready;
// [6291456, 35651584) feat bf16 natural [4096][7][1024].  Total 71.3 MB.

typedef __attribute__((ext_vector_type(4))) float f32x4;
typedef __attribute__((ext_vector_type(8))) short short8;
typedef __attribute__((ext_vector_type(8))) __bf16 bf16x8;

__device__ inline unsigned short f2bf(float f) {
  union { float f; uint32_t u; } x; x.f = f;
  uint32_t u = x.u;
  return (unsigned short)((u + 0x7fffu + ((u >> 16) & 1u)) >> 16);
}

// ---------------- out init: out[b][p][c] = b2(part(p))[c] ----------------
__global__ void init_out(float* __restrict__ out,
                         const float* __restrict__ sb2,
                         const float* __restrict__ db2) {
  int i = blockIdx.x * 256 + threadIdx.x;
  if (i >= 180224) return;
  int c = i & 1;
  int p = (i >> 1) % 22;
  float v;
  if (p < 3)       v = sb2[0 + c];
  else if (p == 3) v = sb2[2 + c];
  else if (p == 4) v = sb2[4 + c];
  else if (p < 19) v = db2[c];
  else             v = sb2[6 + c];
  out[i] = v;
}

// ---------------- weight prep: f32 -> bf16, fragment-ready layout --------
// Per (kstep, coltile) 32KB tile, 16B chunk index c2 = kk*1024+nblk*64+kgrp*16+j15
//   k = kstep*64 + kk*32 + kgrp*8 + e (e=0..7) ; j = coltile*256 + nblk*16 + j15
__global__ void prep_weights(const float* __restrict__ sw1,
                             const float* __restrict__ dw1,
                             unsigned short* __restrict__ wp) {
  int c = blockIdx.x * 256 + threadIdx.x;  // 786432 chunks total
  const float* W;
  size_t ob;
  int local;
  if (c < 524288) {
    int net = c >> 17;
    local = c & 131071;
    W = sw1 + (size_t)net * 1048576;
    ob = (size_t)net * 1048576;
  } else {
    local = c - 524288;
    W = dw1;
    ob = 4194304;
  }
  int c2 = local & 2047;
  int tile = local >> 11;
  int ct = tile & 3;
  int kstep = tile >> 2;
  int kk = c2 >> 10, nblk = (c2 >> 6) & 15, kgrp = (c2 >> 4) & 3, j15 = c2 & 15;
  int kb = kstep * 64 + kk * 32 + kgrp * 8;
  int j = ct * 256 + nblk * 16 + j15;
  short8 v;
#pragma unroll
  for (int e = 0; e < 8; e++) v[e] = (short)f2bf(W[(size_t)(kb + e) * 1024 + j]);
  *(short8*)(wp + ob + (size_t)local * 8) = v;
}

// ---------------- feat prep: f32 -> bf16, natural layout ----------------
__global__ void prep_feat(const float* __restrict__ feat,
                          unsigned short* __restrict__ fb) {
  int i = blockIdx.x * 256 + threadIdx.x;  // 3670016 chunks of 8
  const float* s = feat + (size_t)i * 8;
  f32x4 a = *(const f32x4*)s;
  f32x4 b = *(const f32x4*)(s + 4);
  short8 v;
  v[0] = (short)f2bf(a[0]); v[1] = (short)f2bf(a[1]);
  v[2] = (short)f2bf(a[2]); v[3] = (short)f2bf(a[3]);
  v[4] = (short)f2bf(b[0]); v[5] = (short)f2bf(b[1]);
  v[6] = (short)f2bf(b[2]); v[7] = (short)f2bf(b[3]);
  *(short8*)(fb + (size_t)i * 8) = v;
}

// ---------------- fused main: 128 rows x 256 cols per block -------------
__global__ __launch_bounds__(256) void fused_main(
    const float* __restrict__ sb1, const float* __restrict__ sw2,
    const float* __restrict__ db1, const float* __restrict__ dw2,
    const unsigned short* __restrict__ wp,
    const unsigned short* __restrict__ fb, float* __restrict__ out) {
  __shared__ short8 Abuf[1024];   // 16 KB: 128 rows x 64 k, fragment-ready
  __shared__ short8 Bbuf[2048];   // 32 KB: 64 k x 256 j, fragment-ready

  const int tid = threadIdx.x;
  const int lane = tid & 63;
  const int wid = tid >> 6;
  const int rh = wid >> 1;   // row-half of block (64 rows)
  const int ch = wid & 1;    // col-half of block (128 cols)
  const int r15 = lane & 15;

  // bijective XCD swizzle: 2816 blocks = 8 * 352
  const int bid = blockIdx.x;
  const int swz = (bid & 7) * 352 + (bid >> 3);
  const int ct = swz & 3;    // hidden-col tile (256 cols)
  const int rt = swz >> 2;   // row tile (128 rows)

  int task, nsteps, rbase;
  const unsigned short* wpt;
  const float* b1;
  const float* w2;
  if (rt < 96)        { task = 0; rbase = rt * 128;         wpt = wp;           b1 = sb1;        w2 = sw2;        nsteps = 16; }
  else if (rt < 128)  { task = 1; rbase = (rt - 96) * 128;  wpt = wp + 1048576; b1 = sb1 + 1024; w2 = sw2 + 2048; nsteps = 16; }
  else if (rt < 160)  { task = 2; rbase = (rt - 128) * 128; wpt = wp + 2097152; b1 = sb1 + 2048; w2 = sw2 + 4096; nsteps = 16; }
  else if (rt < 608)  { task = 3; rbase = (rt - 160) * 128; wpt = wp + 4194304; b1 = db1;        w2 = dw2;        nsteps = 32; }
  else                { task = 4; rbase = (rt - 608) * 128; wpt = wp + 3145728; b1 = sb1 + 3072; w2 = sw2 + 6144; nsteps = 16; }

  // A staging row pointers: rowset rs in {0,1}; this thread stages
  // row_l = (rs*4+wid)*16 + r15 with k-chunk (lane>>4)*8 folded in.
  const unsigned short *p00, *p01, *p10, *p11;
  {
    int kl = (lane >> 4) * 8;
#pragma unroll
    for (int rs = 0; rs < 2; rs++) {
      int arow = rbase + (rs * 4 + wid) * 16 + r15;
      int ab, as1, as2;
      if (task == 0 || task == 4) {
        ab = arow / 3; int s = arow - ab * 3; as1 = s; as2 = s;
      } else if (task == 3) {
        ab = arow / 14; int pp = arow - ab * 14;
        if (pp < 12) { as1 = pp >> 2; as2 = 3 + (pp & 3); }
        else         { as1 = 4;       as2 = (pp == 12) ? 5 : 6; }
      } else {
        ab = arow; as1 = 6; as2 = 6;
      }
      const unsigned short* q0 = fb + ((size_t)ab * 7 + as1) * 1024 + kl;
      const unsigned short* q1 = fb + ((size_t)ab * 7 + as2) * 1024 + kl;
      if (rs == 0) { p00 = q0; p01 = q1; } else { p10 = q0; p11 = q1; }
    }
  }

  f32x4 acc[4][8] = {};

#define GLL(SRC, DSTOFF)                                                      \
  __builtin_amdgcn_global_load_lds(                                           \
      (const __attribute__((address_space(1))) void*)(SRC),                   \
      (__attribute__((address_space(3))) void*)((char*)Abuf + (DSTOFF)), 16, 0, 0)

  for (int ks = 0; ks < nsteps; ks++) {
    const int ko = (ks & 15) * 64;
    const unsigned short* a0 = (ks < 16) ? p00 : p01;
    const unsigned short* a1 = (ks < 16) ? p10 : p11;
    // ---- A: 4 batches (kk,rowset): chunk base t*256 + wid*64 ----
    GLL(a0 + ko,      ((0 * 256 + wid * 64) * 16));
    GLL(a1 + ko,      ((1 * 256 + wid * 64) * 16));
    GLL(a0 + ko + 32, ((2 * 256 + wid * 64) * 16));
    GLL(a1 + ko + 32, ((3 * 256 + wid * 64) * 16));
    // ---- B: 8 batches into Bbuf ----
    const unsigned short* wsrc = wpt + (size_t)(ks * 4 + ct) * 16384;
#pragma unroll
    for (int i = 0; i < 8; i++) {
      __builtin_amdgcn_global_load_lds(
          (const __attribute__((address_space(1))) void*)(wsrc + i * 2048 + tid * 8),
          (__attribute__((address_space(3))) void*)((char*)Bbuf + i * 4096 + wid * 1024),
          16, 0, 0);
    }
    __syncthreads();
#pragma unroll
    for (int kk = 0; kk < 2; kk++) {
      short8 afr[4], bfr[8];
#pragma unroll
      for (int m = 0; m < 4; m++)
        afr[m] = Abuf[kk * 512 + (rh * 4 + m) * 64 + (lane >> 4) * 16 + r15];
#pragma unroll
      for (int n = 0; n < 8; n++)
        bfr[n] = Bbuf[kk * 1024 + (ch * 8 + n) * 64 + (lane >> 4) * 16 + r15];
#pragma unroll
      for (int m = 0; m < 4; m++)
#pragma unroll
        for (int n = 0; n < 8; n++)
          acc[m][n] = __builtin_amdgcn_mfma_f32_16x16x32_bf16(
              __builtin_bit_cast(bf16x8, afr[m]),
              __builtin_bit_cast(bf16x8, bfr[n]), acc[m][n], 0, 0, 0);
    }
    __syncthreads();
  }
#undef GLL

  // ---- epilogue: h = relu(acc + b1); partial out = h . w2 ; atomicAdd ----
  float b1v[8], w20v[8], w21v[8];
#pragma unroll
  for (int n = 0; n < 8; n++) {
    int j = ct * 256 + ch * 128 + n * 16 + r15;
    b1v[n] = b1[j];
    w20v[n] = w2[2 * j];
    w21v[n] = w2[2 * j + 1];
  }
#pragma unroll
  for (int m = 0; m < 4; m++) {
#pragma unroll
    for (int r = 0; r < 4; r++) {
      float s0 = 0.f, s1 = 0.f;
#pragma unroll
      for (int n = 0; n < 8; n++) {
        float h = acc[m][n][r] + b1v[n];
        h = fmaxf(h, 0.f);
        s0 = fmaf(h, w20v[n], s0);
        s1 = fmaf(h, w21v[n], s1);
      }
#pragma unroll
      for (int off = 1; off < 16; off <<= 1) {
        s0 += __shfl_xor(s0, off, 64);
        s1 += __shfl_xor(s1, off, 64);
      }
      if (r15 == 0) {
        int rg = rbase + rh * 64 + m * 16 + (lane >> 4) * 4 + r;
        int b, p;
        if (task == 0)      { b = rg / 3;  p = rg - b * 3; }
        else if (task == 1) { b = rg;      p = 3; }
        else if (task == 2) { b = rg;      p = 4; }
        else if (task == 3) { b = rg / 14; p = 5 + (rg - b * 14); }
        else                { b = rg / 3;  p = 19 + (rg - b * 3); }
        atomicAdd(out + ((size_t)b * 44 + p * 2), s0);
        atomicAdd(out + ((size_t)b * 44 + p * 2 + 1), s1);
      }
    }
  }
}

extern "C" void kernel_launch(void* const* d_in, const int* in_sizes, int n_in,
                              void* d_out, int out_size, void* d_ws, size_t ws_size,
                              hipStream_t stream) {
  const float* feat = (const float*)d_in[0];
  const float* sw1  = (const float*)d_in[1];
  const float* sb1  = (const float*)d_in[2];
  const float* sw2  = (const float*)d_in[3];
  const float* sb2  = (const float*)d_in[4];
  const float* dw1  = (const float*)d_in[5];
  const float* db1  = (const float*)d_in[6];
  const float* dw2  = (const float*)d_in[7];
  const float* db2  = (const float*)d_in[8];
  float* out = (float*)d_out;
  unsigned short* wp = (unsigned short*)d_ws;      // 12.58 MB weights
  unsigned short* fb = wp + 6291456;               // 58.7 MB feat bf16

  init_out<<<704, 256, 0, stream>>>(out, sb2, db2);
  prep_weights<<<3072, 256, 0, stream>>>(sw1, dw1, wp);
  prep_feat<<<14336, 256, 0, stream>>>(feat, fb);
  // 704 row-tiles (96 T0 | 32 T1 | 32 T2 | 448 T3 | 96 T4) x 4 col-tiles
  fused_main<<<2816, 256, 0, stream>>>(sb1, sw2, db1, dw2, wp, fb, out);
}

// Round 3
// 490.815 us; speedup vs baseline: 1.4210x; 1.4210x over previous
//
#include <hip/hip_runtime.h>
#include <hip/hip_bf16.h>
#include <stdint.h>

// SymbolicDecoder fused MLP evaluation, MI355X gfx950.  Round 3.
// = Round 1 geometry (64x64 wave tile, acc 4x4, 3 waves/SIMD)
// + Round 2 ingredients (bf16 feat pre-convert, A via global_load_lds,
//   bijective XCD swizzle).  Round 2's 64x128 wave tile died of register
//   pressure (1 wave/SIMD, Occupancy 10%); this restores occupancy while
//   keeping the zero-VALU staging path.
// d_ws layout (ushorts): [0, 6291456) weights bf16 fragment-ready;
// [6291456, 35651584) feat bf16 natural [4096][7][1024].  Total 71.3 MB.

typedef __attribute__((ext_vector_type(4))) float f32x4;
typedef __attribute__((ext_vector_type(8))) short short8;
typedef __attribute__((ext_vector_type(8))) __bf16 bf16x8;

__device__ inline unsigned short f2bf(float f) {
  union { float f; uint32_t u; } x; x.f = f;
  uint32_t u = x.u;
  return (unsigned short)((u + 0x7fffu + ((u >> 16) & 1u)) >> 16);
}

// ---------------- out init: out[b][p][c] = b2(part(p))[c] ----------------
__global__ void init_out(float* __restrict__ out,
                         const float* __restrict__ sb2,
                         const float* __restrict__ db2) {
  int i = blockIdx.x * 256 + threadIdx.x;
  if (i >= 180224) return;
  int c = i & 1;
  int p = (i >> 1) % 22;
  float v;
  if (p < 3)       v = sb2[0 + c];
  else if (p == 3) v = sb2[2 + c];
  else if (p == 4) v = sb2[4 + c];
  else if (p < 19) v = db2[c];
  else             v = sb2[6 + c];
  out[i] = v;
}

// ---------------- weight prep: f32 -> bf16, fragment-ready layout --------
// Per (kstep, coltile) 32KB tile, 16B chunk c2 = kk*1024+nblk*64+kgrp*16+j15
//   k = kstep*64 + kk*32 + kgrp*8 + e (e=0..7) ; j = coltile*256 + nblk*16 + j15
__global__ void prep_weights(const float* __restrict__ sw1,
                             const float* __restrict__ dw1,
                             unsigned short* __restrict__ wp) {
  int c = blockIdx.x * 256 + threadIdx.x;  // 786432 chunks total
  const float* W;
  size_t ob;
  int local;
  if (c < 524288) {
    int net = c >> 17;
    local = c & 131071;
    W = sw1 + (size_t)net * 1048576;
    ob = (size_t)net * 1048576;
  } else {
    local = c - 524288;
    W = dw1;
    ob = 4194304;
  }
  int c2 = local & 2047;
  int tile = local >> 11;
  int ct = tile & 3;
  int kstep = tile >> 2;
  int kk = c2 >> 10, nblk = (c2 >> 6) & 15, kgrp = (c2 >> 4) & 3, j15 = c2 & 15;
  int kb = kstep * 64 + kk * 32 + kgrp * 8;
  int j = ct * 256 + nblk * 16 + j15;
  short8 v;
#pragma unroll
  for (int e = 0; e < 8; e++) v[e] = (short)f2bf(W[(size_t)(kb + e) * 1024 + j]);
  *(short8*)(wp + ob + (size_t)local * 8) = v;
}

// ---------------- feat prep: f32 -> bf16, natural layout ----------------
__global__ void prep_feat(const float* __restrict__ feat,
                          unsigned short* __restrict__ fb) {
  int i = blockIdx.x * 256 + threadIdx.x;  // 3670016 chunks of 8
  const float* s = feat + (size_t)i * 8;
  f32x4 a = *(const f32x4*)s;
  f32x4 b = *(const f32x4*)(s + 4);
  short8 v;
  v[0] = (short)f2bf(a[0]); v[1] = (short)f2bf(a[1]);
  v[2] = (short)f2bf(a[2]); v[3] = (short)f2bf(a[3]);
  v[4] = (short)f2bf(b[0]); v[5] = (short)f2bf(b[1]);
  v[6] = (short)f2bf(b[2]); v[7] = (short)f2bf(b[3]);
  *(short8*)(fb + (size_t)i * 8) = v;
}

// ---------------- fused main: 64 rows x 256 cols per block --------------
__global__ __launch_bounds__(256) void fused_main(
    const float* __restrict__ sb1, const float* __restrict__ sw2,
    const float* __restrict__ db1, const float* __restrict__ dw2,
    const unsigned short* __restrict__ wp,
    const unsigned short* __restrict__ fb, float* __restrict__ out) {
  __shared__ short8 Abuf[512];    // 8 KB : 64 rows x 64 k, fragment-ready
  __shared__ short8 Bbuf[2048];   // 32 KB: 64 k x 256 j, fragment-ready

  const int tid = threadIdx.x;
  const int lane = tid & 63;
  const int wid = tid >> 6;
  const int r15 = lane & 15;

  // bijective XCD swizzle: 5632 blocks = 8 * 704
  const int bid = blockIdx.x;
  const int swz = (bid & 7) * 704 + (bid >> 3);
  const int ct = swz & 3;    // hidden-col tile (256 cols)
  const int rt = swz >> 2;   // row tile (64 rows)

  int task, nsteps, rbase;
  const unsigned short* wpt;
  const float* b1;
  const float* w2;
  if (rt < 192)       { task = 0; rbase = rt * 64;          wpt = wp;           b1 = sb1;        w2 = sw2;        nsteps = 16; }
  else if (rt < 256)  { task = 1; rbase = (rt - 192) * 64;  wpt = wp + 1048576; b1 = sb1 + 1024; w2 = sw2 + 2048; nsteps = 16; }
  else if (rt < 320)  { task = 2; rbase = (rt - 256) * 64;  wpt = wp + 2097152; b1 = sb1 + 2048; w2 = sw2 + 4096; nsteps = 16; }
  else if (rt < 1216) { task = 3; rbase = (rt - 320) * 64;  wpt = wp + 4194304; b1 = db1;        w2 = dw2;        nsteps = 32; }
  else                { task = 4; rbase = (rt - 1216) * 64; wpt = wp + 3145728; b1 = sb1 + 3072; w2 = sw2 + 6144; nsteps = 16; }

  // A staging: thread (wid,lane) owns row rbase + wid*16 + (lane&15),
  // k-chunk (lane>>4)*8.  Two GLL batches per k-step: kk=0 (k+0), kk=1 (k+32).
  const unsigned short *p0, *p1;
  {
    int arow = rbase + wid * 16 + r15;
    int ab, as1, as2;
    if (task == 0 || task == 4) {
      ab = arow / 3; int s = arow - ab * 3; as1 = s; as2 = s;
    } else if (task == 3) {
      ab = arow / 14; int pp = arow - ab * 14;
      if (pp < 12) { as1 = pp >> 2; as2 = 3 + (pp & 3); }
      else         { as1 = 4;       as2 = (pp == 12) ? 5 : 6; }
    } else {
      ab = arow; as1 = 6; as2 = 6;
    }
    int kl = (lane >> 4) * 8;
    p0 = fb + ((size_t)ab * 7 + as1) * 1024 + kl;
    p1 = fb + ((size_t)ab * 7 + as2) * 1024 + kl;
  }

  f32x4 acc[4][4] = {};

  for (int ks = 0; ks < nsteps; ks++) {
    const int ko = (ks & 15) * 64;
    const unsigned short* a = (ks < 16) ? p0 : p1;
    // ---- A: 2 batches (kk=0,1); chunk base kk*256 + wid*64 ----
    __builtin_amdgcn_global_load_lds(
        (const __attribute__((address_space(1))) void*)(a + ko),
        (__attribute__((address_space(3))) void*)((char*)Abuf + wid * 1024),
        16, 0, 0);
    __builtin_amdgcn_global_load_lds(
        (const __attribute__((address_space(1))) void*)(a + ko + 32),
        (__attribute__((address_space(3))) void*)((char*)Abuf + 4096 + wid * 1024),
        16, 0, 0);
    // ---- B: 8 batches into Bbuf ----
    const unsigned short* wsrc = wpt + (size_t)(ks * 4 + ct) * 16384;
#pragma unroll
    for (int i = 0; i < 8; i++) {
      __builtin_amdgcn_global_load_lds(
          (const __attribute__((address_space(1))) void*)(wsrc + i * 2048 + tid * 8),
          (__attribute__((address_space(3))) void*)((char*)Bbuf + i * 4096 + wid * 1024),
          16, 0, 0);
    }
    __syncthreads();
    // ---- MFMA: wave w owns cols [w*64, w*64+64) of the 256-col tile ----
#pragma unroll
    for (int kk = 0; kk < 2; kk++) {
      short8 afr[4], bfr[4];
#pragma unroll
      for (int m = 0; m < 4; m++)
        afr[m] = Abuf[kk * 256 + m * 64 + (lane >> 4) * 16 + r15];
#pragma unroll
      for (int n = 0; n < 4; n++)
        bfr[n] = Bbuf[kk * 1024 + (wid * 4 + n) * 64 + (lane >> 4) * 16 + r15];
#pragma unroll
      for (int m = 0; m < 4; m++)
#pragma unroll
        for (int n = 0; n < 4; n++)
          acc[m][n] = __builtin_amdgcn_mfma_f32_16x16x32_bf16(
              __builtin_bit_cast(bf16x8, afr[m]),
              __builtin_bit_cast(bf16x8, bfr[n]), acc[m][n], 0, 0, 0);
    }
    __syncthreads();
  }

  // ---- epilogue: h = relu(acc + b1); partial out = h . w2 ; atomicAdd ----
  float b1v[4], w20v[4], w21v[4];
#pragma unroll
  for (int n = 0; n < 4; n++) {
    int j = ct * 256 + wid * 64 + n * 16 + r15;
    b1v[n] = b1[j];
    w20v[n] = w2[2 * j];
    w21v[n] = w2[2 * j + 1];
  }
#pragma unroll
  for (int m = 0; m < 4; m++) {
#pragma unroll
    for (int r = 0; r < 4; r++) {
      float s0 = 0.f, s1 = 0.f;
#pragma unroll
      for (int n = 0; n < 4; n++) {
        float h = acc[m][n][r] + b1v[n];
        h = fmaxf(h, 0.f);
        s0 = fmaf(h, w20v[n], s0);
        s1 = fmaf(h, w21v[n], s1);
      }
#pragma unroll
      for (int off = 1; off < 16; off <<= 1) {
        s0 += __shfl_xor(s0, off, 64);
        s1 += __shfl_xor(s1, off, 64);
      }
      if (r15 == 0) {
        int rg = rbase + m * 16 + (lane >> 4) * 4 + r;
        int b, p;
        if (task == 0)      { b = rg / 3;  p = rg - b * 3; }
        else if (task == 1) { b = rg;      p = 3; }
        else if (task == 2) { b = rg;      p = 4; }
        else if (task == 3) { b = rg / 14; p = 5 + (rg - b * 14); }
        else                { b = rg / 3;  p = 19 + (rg - b * 3); }
        atomicAdd(out + ((size_t)b * 44 + p * 2), s0);
        atomicAdd(out + ((size_t)b * 44 + p * 2 + 1), s1);
      }
    }
  }
}

extern "C" void kernel_launch(void* const* d_in, const int* in_sizes, int n_in,
                              void* d_out, int out_size, void* d_ws, size_t ws_size,
                              hipStream_t stream) {
  const float* feat = (const float*)d_in[0];
  const float* sw1  = (const float*)d_in[1];
  const float* sb1  = (const float*)d_in[2];
  const float* sw2  = (const float*)d_in[3];
  const float* sb2  = (const float*)d_in[4];
  const float* dw1  = (const float*)d_in[5];
  const float* db1  = (const float*)d_in[6];
  const float* dw2  = (const float*)d_in[7];
  const float* db2  = (const float*)d_in[8];
  float* out = (float*)d_out;
  unsigned short* wp = (unsigned short*)d_ws;      // 12.58 MB weights
  unsigned short* fb = wp + 6291456;               // 58.7 MB feat bf16

  init_out<<<704, 256, 0, stream>>>(out, sb2, db2);
  prep_weights<<<3072, 256, 0, stream>>>(sw1, dw1, wp);
  prep_feat<<<14336, 256, 0, stream>>>(feat, fb);
  // 1408 row-tiles (192 T0 | 64 T1 | 64 T2 | 896 T3 | 192 T4) x 4 col-tiles
  fused_main<<<5632, 256, 0, stream>>>(sb1, sw2, db1, dw2, wp, fb, out);
}